// Round 10
// baseline (169.148 us; speedup 1.0000x reference)
//
#include <hip/hip_runtime.h>
#include <hip/hip_bf16.h>

// MaskedAttentionHead: x[4,4096,1024] fp32 -> out fp32 [4,4096,64]
// Round 9: resubmit of round-8 (GPU acquisition timed out; no bench signal).
// attn processes TWO adjacent q-tiles per block (shared K/V staging + shared
// K-fragment reads feed both QK^T's). 4-tile chunks, 272-pair grid, LPT.
// Combine merges up to 16 chunks. proj/prep_w unchanged.

typedef _Float16 f16;
typedef f16 half4 __attribute__((ext_vector_type(4)));
typedef f16 half8 __attribute__((ext_vector_type(8)));
typedef float f32x4 __attribute__((ext_vector_type(4)));

#define T_SEQ 4096
// 0.125 (1/sqrt(64)) * log2(e): softmax computed in exp2 domain
#define QSCL 0.1803368801111204f

__device__ __forceinline__ f32x4 mfma16(half8 a, half8 b, f32x4 c) {
    return __builtin_amdgcn_mfma_f32_16x16x32_f16(a, b, c, 0, 0, 0);
}

// ---- Kernel 1: pack W into fragment order Wfrag[nt][ks][lane][8] f16 ----
__global__ __launch_bounds__(256) void prep_w(const float* __restrict__ Wq,
                                              const float* __restrict__ Wk,
                                              const float* __restrict__ Wv,
                                              f16* __restrict__ Wfrag) {
    int nt = blockIdx.x;               // 0..11
    int mat = nt >> 2;
    const float* W = (mat == 0) ? Wq : (mat == 1 ? Wk : Wv);
    float s = (mat == 0) ? QSCL : 1.0f;
    int tid = threadIdx.x;
    int lane = tid & 63, g = lane >> 4, c16 = lane & 15;
    int ksb = (tid >> 6) * 8;
    int h = ((nt & 3) << 4) + c16;
#pragma unroll
    for (int q = 0; q < 8; ++q) {
        int ks = ksb + q;
        half8 o;
#pragma unroll
        for (int j = 0; j < 8; ++j) {
            int k = ks * 32 + g * 8 + j;
            o[j] = (f16)(W[(size_t)k * 64 + h] * s);
        }
        *reinterpret_cast<half8*>(&Wfrag[((size_t)(nt * 32 + ks) * 64 + lane) * 8]) = o;
    }
}

// ---- Kernel 2: QKV projection with one-shot LDS x-staging (unchanged) ----
__global__ __launch_bounds__(256, 4) void proj(const float* __restrict__ x,
                                               const f16* __restrict__ Wfrag,
                                               const float* __restrict__ bk,
                                               const float* __restrict__ bq,
                                               const float* __restrict__ bv,
                                               f16* __restrict__ Qb, f16* __restrict__ Kb,
                                               f16* __restrict__ Vbt) {
    __shared__ f16 xs[16][1032];
    int m0 = blockIdx.x << 4;
    int tid = threadIdx.x;
    int w = tid >> 6, lane = tid & 63, g = lane >> 4, c16 = lane & 15;
    {
        int row = tid >> 4;
        int c0 = (tid & 15) << 2;
        const float* xr = &x[(size_t)(m0 + row) * 1024 + c0];
#pragma unroll
        for (int chunk = 0; chunk < 8; ++chunk) {
            float4 A = *reinterpret_cast<const float4*>(xr + chunk * 128);
            float4 B = *reinterpret_cast<const float4*>(xr + chunk * 128 + 64);
            half4 ha, hb;
            ha[0] = (f16)A.x; ha[1] = (f16)A.y; ha[2] = (f16)A.z; ha[3] = (f16)A.w;
            hb[0] = (f16)B.x; hb[1] = (f16)B.y; hb[2] = (f16)B.z; hb[3] = (f16)B.w;
            *reinterpret_cast<half4*>(&xs[row][c0 + chunk * 128]) = ha;
            *reinterpret_cast<half4*>(&xs[row][c0 + chunk * 128 + 64]) = hb;
        }
    }
    __syncthreads();
    f32x4 zero = {0.f, 0.f, 0.f, 0.f};
    f32x4 acc[3];
#pragma unroll
    for (int i = 0; i < 3; ++i) acc[i] = zero;
    const f16* wbase = &Wfrag[(size_t)(w * 3) * 32 * 64 * 8 + (size_t)lane * 8];
#pragma unroll 8
    for (int ks = 0; ks < 32; ++ks) {
        half8 a = *reinterpret_cast<const half8*>(&xs[c16][ks * 32 + g * 8]);
#pragma unroll
        for (int i = 0; i < 3; ++i) {
            half8 bf = *reinterpret_cast<const half8*>(
                wbase + ((size_t)i * 32 + ks) * 64 * 8);
            acc[i] = mfma16(a, bf, acc[i]);
        }
    }
    int b = m0 >> 12;
#pragma unroll
    for (int i = 0; i < 3; ++i) {
        int nt = w * 3 + i;
        int mat = nt >> 2;
        int h = ((nt & 3) << 4) + c16;
        float bias = (mat == 0) ? bq[h] * QSCL : (mat == 1 ? bk[h] : bv[h]);
#pragma unroll
        for (int j = 0; j < 4; ++j) {
            int row = m0 + g * 4 + j;
            f16 val = (f16)(acc[i][j] + bias);
            if (mat == 0) Qb[(size_t)row * 64 + h] = val;
            else if (mat == 1) Kb[(size_t)row * 64 + h] = val;
            else Vbt[((size_t)(b * 64 + h)) * 4096 + (row & 4095)] = val;
        }
    }
}

// ---- Kernel 3: flash attention, 2 q-tiles/block, 64 keys/iter, 4-tile chunks ----
// Grid x = 272 (qt-pair, chunk) entries: band m (pairs 2m, 2m+1) has m+1 chunks each.
__global__ __launch_bounds__(256) void attn(const f16* __restrict__ Qb,
                                            const f16* __restrict__ Kb,
                                            const f16* __restrict__ Vbt,
                                            f16* __restrict__ Opart,
                                            float* __restrict__ Ml) {
    int rem = 271 - (int)blockIdx.x;      // LPT: largest qt-pair first
    int qtp = 0, ck = 0;
#pragma unroll
    for (int m = 0; m < 16; ++m) {
        int cnt = 2 * (m + 1);
        if (rem < cnt) {
            if (rem >= m + 1) { qtp = 2 * m + 1; ck = rem - (m + 1); }
            else { qtp = 2 * m; ck = rem; }
            break;
        }
        rem -= cnt;
    }
    int qtA = qtp * 2, qtB = qtp * 2 + 1;
    int b = blockIdx.y;
    int t0 = ck << 2;                      // first KV tile of this chunk
    int nIter = min(4, qtB - t0 + 1);
    int q0A = qtA << 6, q0B = qtB << 6;
    const f16* Q = Qb + (size_t)b * T_SEQ * 64;
    const f16* K = Kb + (size_t)b * T_SEQ * 64;
    const f16* Vg = Vbt + (size_t)b * 64 * T_SEQ;
    int tid = threadIdx.x;
    int w = tid >> 6, lane = tid & 63, g = lane >> 4, c16 = lane & 15;
    __shared__ f16 Kt[2][64][72];   // [buf][key][h]
    __shared__ f16 Vt[2][64][72];   // [buf][h][key]
    __shared__ f16 Pl[4][16][72];   // [wave][qrow][key] (shared A then B)

    int qrA = q0A + 16 * w + c16, qrB = q0B + 16 * w + c16;
    half8 qfA0 = *reinterpret_cast<const half8*>(&Q[(size_t)qrA * 64 + g * 8]);
    half8 qfA1 = *reinterpret_cast<const half8*>(&Q[(size_t)qrA * 64 + 32 + g * 8]);
    half8 qfB0 = *reinterpret_cast<const half8*>(&Q[(size_t)qrB * 64 + g * 8]);
    half8 qfB1 = *reinterpret_cast<const half8*>(&Q[(size_t)qrB * 64 + 32 + g * 8]);

    f32x4 zero = {0.f, 0.f, 0.f, 0.f};
    f32x4 oaccA[4], oaccB[4];
#pragma unroll
    for (int i = 0; i < 4; ++i) { oaccA[i] = zero; oaccB[i] = zero; }
    float mA = -__builtin_inff(), lA = 0.f;
    float mB = -__builtin_inff(), lB = 0.f;

    int sr = tid >> 2, sc = (tid & 3) << 4;
    int k0 = t0 << 6;
    half8 kr0 = *reinterpret_cast<const half8*>(&K[(size_t)(k0 + sr) * 64 + sc]);
    half8 kr1 = *reinterpret_cast<const half8*>(&K[(size_t)(k0 + sr) * 64 + sc + 8]);
    half8 vr0 = *reinterpret_cast<const half8*>(&Vg[(size_t)sr * T_SEQ + k0 + sc]);
    half8 vr1 = *reinterpret_cast<const half8*>(&Vg[(size_t)sr * T_SEQ + k0 + sc + 8]);
    *reinterpret_cast<half8*>(&Kt[0][sr][sc]) = kr0;
    *reinterpret_cast<half8*>(&Kt[0][sr][sc + 8]) = kr1;
    *reinterpret_cast<half8*>(&Vt[0][sr][sc]) = vr0;
    *reinterpret_cast<half8*>(&Vt[0][sr][sc + 8]) = vr1;
    __syncthreads();
    int cur = 0;

    for (int it = 0; it < nIter; ++it) {
        int gt = t0 + it;
        bool doA = (gt <= qtA);
        if (it + 1 < nIter) {
            int kn = (gt + 1) << 6;
            kr0 = *reinterpret_cast<const half8*>(&K[(size_t)(kn + sr) * 64 + sc]);
            kr1 = *reinterpret_cast<const half8*>(&K[(size_t)(kn + sr) * 64 + sc + 8]);
            vr0 = *reinterpret_cast<const half8*>(&Vg[(size_t)sr * T_SEQ + kn + sc]);
            vr1 = *reinterpret_cast<const half8*>(&Vg[(size_t)sr * T_SEQ + kn + sc + 8]);
        }
        // S^T = K · Q^T, K-fragments shared between the two q-tiles
        f32x4 sA[4], sB[4];
#pragma unroll
        for (int nt = 0; nt < 4; ++nt) { sA[nt] = zero; sB[nt] = zero; }
#pragma unroll
        for (int nt = 0; nt < 4; ++nt) {
            half8 kf0 = *reinterpret_cast<const half8*>(&Kt[cur][nt * 16 + c16][g * 8]);
            half8 kf1 = *reinterpret_cast<const half8*>(&Kt[cur][nt * 16 + c16][32 + g * 8]);
            sB[nt] = mfma16(kf0, qfB0, sB[nt]);
            sB[nt] = mfma16(kf1, qfB1, sB[nt]);
            if (doA) {
                sA[nt] = mfma16(kf0, qfA0, sA[nt]);
                sA[nt] = mfma16(kf1, qfA1, sA[nt]);
            }
        }
        int kb = gt << 6;
        // ---------------- tile A ----------------
        if (doA) {
            if (gt == qtA) {
#pragma unroll
                for (int nt = 0; nt < 4; ++nt)
#pragma unroll
                    for (int jj = 0; jj < 4; ++jj)
                        if (kb + nt * 16 + g * 4 + jj > qrA) sA[nt][jj] = -1e30f;
            }
            float mx;
            {
                f32x4 e = __builtin_elementwise_max(
                    __builtin_elementwise_max(sA[0], sA[1]),
                    __builtin_elementwise_max(sA[2], sA[3]));
                mx = fmaxf(fmaxf(e[0], e[1]), fmaxf(e[2], e[3]));
            }
            mx = fmaxf(mx, __shfl_xor(mx, 16, 64));
            mx = fmaxf(mx, __shfl_xor(mx, 32, 64));
            float nm = fmaxf(mA, mx);
            float al = exp2f(mA - nm);
            mA = nm;
            float rs = 0.f;
#pragma unroll
            for (int nt = 0; nt < 4; ++nt) {
                float s0 = exp2f(sA[nt][0] - mA);
                float s1 = exp2f(sA[nt][1] - mA);
                float s2 = exp2f(sA[nt][2] - mA);
                float s3 = exp2f(sA[nt][3] - mA);
                sA[nt][0] = s0; sA[nt][1] = s1; sA[nt][2] = s2; sA[nt][3] = s3;
                rs += (s0 + s1) + (s2 + s3);
            }
            rs += __shfl_xor(rs, 16, 64);
            rs += __shfl_xor(rs, 32, 64);
            lA = lA * al + rs;
#pragma unroll
            for (int ht = 0; ht < 4; ++ht)
#pragma unroll
                for (int jj = 0; jj < 4; ++jj) oaccA[ht][jj] *= al;
#pragma unroll
            for (int nt = 0; nt < 4; ++nt) {
                half4 p4;
                p4[0] = (f16)sA[nt][0]; p4[1] = (f16)sA[nt][1];
                p4[2] = (f16)sA[nt][2]; p4[3] = (f16)sA[nt][3];
                *reinterpret_cast<half4*>(&Pl[w][c16][nt * 16 + g * 4]) = p4;
            }
            half8 pa0 = *reinterpret_cast<const half8*>(&Pl[w][c16][g * 8]);
            half8 pa1 = *reinterpret_cast<const half8*>(&Pl[w][c16][32 + g * 8]);
#pragma unroll
            for (int ht = 0; ht < 4; ++ht) {
                half8 vb0 = *reinterpret_cast<const half8*>(&Vt[cur][ht * 16 + c16][g * 8]);
                half8 vb1 = *reinterpret_cast<const half8*>(&Vt[cur][ht * 16 + c16][32 + g * 8]);
                oaccA[ht] = mfma16(vb0, pa0, oaccA[ht]);
                oaccA[ht] = mfma16(vb1, pa1, oaccA[ht]);
            }
        }
        // ---------------- tile B ----------------
        {
            if (gt == qtB) {
#pragma unroll
                for (int nt = 0; nt < 4; ++nt)
#pragma unroll
                    for (int jj = 0; jj < 4; ++jj)
                        if (kb + nt * 16 + g * 4 + jj > qrB) sB[nt][jj] = -1e30f;
            }
            float mx;
            {
                f32x4 e = __builtin_elementwise_max(
                    __builtin_elementwise_max(sB[0], sB[1]),
                    __builtin_elementwise_max(sB[2], sB[3]));
                mx = fmaxf(fmaxf(e[0], e[1]), fmaxf(e[2], e[3]));
            }
            mx = fmaxf(mx, __shfl_xor(mx, 16, 64));
            mx = fmaxf(mx, __shfl_xor(mx, 32, 64));
            float nm = fmaxf(mB, mx);
            float al = exp2f(mB - nm);
            mB = nm;
            float rs = 0.f;
#pragma unroll
            for (int nt = 0; nt < 4; ++nt) {
                float s0 = exp2f(sB[nt][0] - mB);
                float s1 = exp2f(sB[nt][1] - mB);
                float s2 = exp2f(sB[nt][2] - mB);
                float s3 = exp2f(sB[nt][3] - mB);
                sB[nt][0] = s0; sB[nt][1] = s1; sB[nt][2] = s2; sB[nt][3] = s3;
                rs += (s0 + s1) + (s2 + s3);
            }
            rs += __shfl_xor(rs, 16, 64);
            rs += __shfl_xor(rs, 32, 64);
            lB = lB * al + rs;
#pragma unroll
            for (int ht = 0; ht < 4; ++ht)
#pragma unroll
                for (int jj = 0; jj < 4; ++jj) oaccB[ht][jj] *= al;
#pragma unroll
            for (int nt = 0; nt < 4; ++nt) {
                half4 p4;
                p4[0] = (f16)sB[nt][0]; p4[1] = (f16)sB[nt][1];
                p4[2] = (f16)sB[nt][2]; p4[3] = (f16)sB[nt][3];
                *reinterpret_cast<half4*>(&Pl[w][c16][nt * 16 + g * 4]) = p4;
            }
            half8 pa0 = *reinterpret_cast<const half8*>(&Pl[w][c16][g * 8]);
            half8 pa1 = *reinterpret_cast<const half8*>(&Pl[w][c16][32 + g * 8]);
#pragma unroll
            for (int ht = 0; ht < 4; ++ht) {
                half8 vb0 = *reinterpret_cast<const half8*>(&Vt[cur][ht * 16 + c16][g * 8]);
                half8 vb1 = *reinterpret_cast<const half8*>(&Vt[cur][ht * 16 + c16][32 + g * 8]);
                oaccB[ht] = mfma16(vb0, pa0, oaccB[ht]);
                oaccB[ht] = mfma16(vb1, pa1, oaccB[ht]);
            }
        }
        if (it + 1 < nIter) {
            *reinterpret_cast<half8*>(&Kt[cur ^ 1][sr][sc]) = kr0;
            *reinterpret_cast<half8*>(&Kt[cur ^ 1][sr][sc + 8]) = kr1;
            *reinterpret_cast<half8*>(&Vt[cur ^ 1][sr][sc]) = vr0;
            *reinterpret_cast<half8*>(&Vt[cur ^ 1][sr][sc + 8]) = vr1;
        }
        __syncthreads();
        cur ^= 1;
    }
    // ---- epilogue: partials for both q-tiles (slot stride 16 chunks/qt) ----
    int r = 16 * w + c16;
    {
        int slot = (((b << 6) + qtA) << 4) + ck;
        f16* Op = Opart + (size_t)slot * 4096;
        float* mlp = Ml + (size_t)slot * 128;
#pragma unroll
        for (int ht = 0; ht < 4; ++ht) {
            half4 o4;
            o4[0] = (f16)oaccA[ht][0]; o4[1] = (f16)oaccA[ht][1];
            o4[2] = (f16)oaccA[ht][2]; o4[3] = (f16)oaccA[ht][3];
            *reinterpret_cast<half4*>(&Op[r * 64 + ht * 16 + g * 4]) = o4;
        }
        if (g == 0) { mlp[r] = mA; mlp[64 + r] = lA; }
    }
    {
        int slot = (((b << 6) + qtB) << 4) + ck;
        f16* Op = Opart + (size_t)slot * 4096;
        float* mlp = Ml + (size_t)slot * 128;
#pragma unroll
        for (int ht = 0; ht < 4; ++ht) {
            half4 o4;
            o4[0] = (f16)oaccB[ht][0]; o4[1] = (f16)oaccB[ht][1];
            o4[2] = (f16)oaccB[ht][2]; o4[3] = (f16)oaccB[ht][3];
            *reinterpret_cast<half4*>(&Op[r * 64 + ht * 16 + g * 4]) = o4;
        }
        if (g == 0) { mlp[r] = mB; mlp[64 + r] = lB; }
    }
}

// ---- Kernel 4: combine split-KV partials (exp2 domain, up to 16 chunks) ----
__global__ __launch_bounds__(256) void combine(const f16* __restrict__ Opart,
                                               const float* __restrict__ Ml,
                                               float* __restrict__ out) {
    int qt = blockIdx.x, b = blockIdx.y;
    int nck = (qt >> 2) + 1;
    int tid = threadIdx.x;
    int row = tid >> 2, c0 = (tid & 3) << 4;
    int bslot = ((b << 6) + qt) << 4;
    float M = -1e30f;
    float mv[16], lv[16];
#pragma unroll
    for (int i = 0; i < 16; ++i)
        if (i < nck) {
            mv[i] = Ml[(size_t)(bslot + i) * 128 + row];
            lv[i] = Ml[(size_t)(bslot + i) * 128 + 64 + row];
            M = fmaxf(M, mv[i]);
        }
    float L = 0.f, sc[16];
#pragma unroll
    for (int i = 0; i < 16; ++i)
        if (i < nck) { sc[i] = exp2f(mv[i] - M); L += lv[i] * sc[i]; }
    float inv = 1.0f / L;
    float o[16];
#pragma unroll
    for (int j = 0; j < 16; ++j) o[j] = 0.f;
#pragma unroll
    for (int i = 0; i < 16; ++i)
        if (i < nck) {
            const f16* Op = Opart + (size_t)(bslot + i) * 4096 + row * 64 + c0;
            half8 h0 = *reinterpret_cast<const half8*>(Op);
            half8 h1 = *reinterpret_cast<const half8*>(Op + 8);
#pragma unroll
            for (int j = 0; j < 8; ++j) {
                o[j] += sc[i] * (float)h0[j];
                o[8 + j] += sc[i] * (float)h1[j];
            }
        }
    float* op = &out[((size_t)b * T_SEQ + (qt << 6) + row) * 64 + c0];
#pragma unroll
    for (int j = 0; j < 16; ++j) op[j] = o[j] * inv;
}

extern "C" void kernel_launch(void* const* d_in, const int* in_sizes, int n_in,
                              void* d_out, int out_size, void* d_ws, size_t ws_size,
                              hipStream_t stream) {
    (void)in_sizes; (void)n_in; (void)out_size; (void)ws_size;
    const float* x  = (const float*)d_in[0];
    const float* Wk = (const float*)d_in[1];
    const float* bk = (const float*)d_in[2];
    const float* Wq = (const float*)d_in[3];
    const float* bq = (const float*)d_in[4];
    const float* Wv = (const float*)d_in[5];
    const float* bv = (const float*)d_in[6];
    float* out = (float*)d_out;
    char* ws = (char*)d_ws;
    f16* Wfrag = (f16*)(ws);                         // 393216 B
    f16* Qb    = (f16*)(ws + 393216);                // 2 MiB
    f16* Kb    = (f16*)(ws + 393216 + 2097152);      // 2 MiB
    f16* Vbt   = (f16*)(ws + 393216 + 2 * 2097152);  // 2 MiB (transposed)
    f16* Opart = (f16*)(ws + 393216 + 3 * 2097152);              // 32 MiB (4096 slots)
    float* Ml  = (float*)(ws + 393216 + 3 * 2097152 + 33554432); // 2 MiB

    prep_w<<<12, 256, 0, stream>>>(Wq, Wk, Wv, Wfrag);
    proj<<<1024, 256, 0, stream>>>(x, Wfrag, bk, bq, bv, Qb, Kb, Vbt);
    attn<<<dim3(272, 4), 256, 0, stream>>>(Qb, Kb, Vbt, Opart, Ml);
    combine<<<dim3(64, 4), 256, 0, stream>>>(Opart, Ml, out);
}